// Round 2
// baseline (129.486 us; speedup 1.0000x reference)
//
#include <hip/hip_runtime.h>
#include <hip/hip_bf16.h>
#include <math.h>

#define WAVE 64
#define K2T 1024
#define KPT 32

__device__ __forceinline__ float wave_sum_f(float x) {
#pragma unroll
  for (int o = 32; o; o >>= 1) x += __shfl_xor(x, o, WAVE);
  return x;
}

__device__ __forceinline__ float wave_incl_scan(float x) {
  const int lane = threadIdx.x & 63;
#pragma unroll
  for (int o = 1; o < 64; o <<= 1) {
    float t = __shfl_up(x, o, WAVE);
    if (lane >= o) x += t;
  }
  return x;
}

// ---------------- Kernel 1: per-row soft-hinge loss ----------------
// l[b] = 1 if target is argmax (margin == 0), else relu(1 - z_y + lse(z))
__global__ void row_loss_kernel(const float* __restrict__ outp,
                                const int* __restrict__ target,
                                float* __restrict__ lv,
                                int B, int C) {
  const int lane = threadIdx.x & (WAVE - 1);
  const int wid  = threadIdx.x >> 6;
  const int row  = blockIdx.x * (blockDim.x >> 6) + wid;
  if (row >= B) return;

  const float* rp = outp + (size_t)row * (size_t)C;
  const float zy = rp[target[row]];

  const int C4 = C >> 2;
  const float4* rp4 = (const float4*)rp;

  float m = -INFINITY;
  for (int i = lane; i < C4; i += WAVE) {
    float4 v = rp4[i];
    m = fmaxf(fmaxf(m, fmaxf(v.x, v.y)), fmaxf(v.z, v.w));
  }
  for (int i = (C4 << 2) + lane; i < C; i += WAVE) m = fmaxf(m, rp[i]);
#pragma unroll
  for (int o = 32; o; o >>= 1) m = fmaxf(m, __shfl_xor(m, o, WAVE));

  float s = 0.f;
  for (int i = lane; i < C4; i += WAVE) {
    float4 v = rp4[i];
    s += __expf(v.x - m) + __expf(v.y - m) + __expf(v.z - m) + __expf(v.w - m);
  }
  for (int i = (C4 << 2) + lane; i < C; i += WAVE) s += __expf(rp[i] - m);
#pragma unroll
  for (int o = 32; o; o >>= 1) s += __shfl_xor(s, o, WAVE);

  if (lane == 0) {
    // margin >= 0  <=>  z_y == row max
    float l = (zy >= m) ? 1.0f : fmaxf(0.0f, 1.0f - zy + m + __logf(s));
    lv[row] = l;
  }
}

// ---------------- Kernel 2: radix-histogram prefix selection ----------------
// Selection over sorted-ascending l is a prefix (cum[i]+i strictly increasing,
// l >= 0). Find the exact crossing BIT PATTERN p* (first value at which the
// predicate S + K - 1 <= B fails) via 3 histogram passes over the float bit
// pattern (8 exp bits, 12 mantissa bits, 11 mantissa bits), then include a
// partial count j of the ties at p*.

// Shared broadcast slots
struct BC {
  unsigned first;     // atomicMin winner tid
  unsigned bin;       // crossing bin of current pass
  float S0, K0;       // exclusive cums before crossing point
  unsigned m;         // tie count at final pattern
  float cn;           // count(l > 1) == count(margin < 0)
  int selectAll;      // predicate never fails
  float totS, totC;   // totals (for selectAll path)
};

// scan bins (hs/hc, nbins = BPT*K2T), find first bin where
// (S0+cumS) + (K0+cumC) - 1 > Bd. Winner updates bc->bin/S0/K0/m.
template <int BPT>
__device__ void find_crossing(const float* hs, const unsigned* hc,
                              float Bd, float S0, float C0,
                              float* wps, float* wpc, BC* bc) {
  const int tid = threadIdx.x, lane = tid & 63, wid = tid >> 6;
  float bs[BPT], bn[BPT];
  float ls = 0.f, lc = 0.f;
#pragma unroll
  for (int i = 0; i < BPT; i++) {
    bs[i] = hs[tid * BPT + i];
    bn[i] = (float)hc[tid * BPT + i];
    ls += bs[i]; lc += bn[i];
  }
  float is = wave_incl_scan(ls);
  float ic = wave_incl_scan(lc);
  if (lane == 63) { wps[wid] = is; wpc[wid] = ic; }
  if (tid == 0) bc->first = 0xFFFFFFFFu;
  __syncthreads();
  if (tid < 16) {
    float x = wps[tid], y = wpc[tid];
    float xs = x, ys = y;
#pragma unroll
    for (int o = 1; o < 16; o <<= 1) {
      float t = __shfl_up(xs, o, WAVE);
      float u = __shfl_up(ys, o, WAVE);
      if (tid >= o) { xs += t; ys += u; }
    }
    wps[tid] = xs - x;   // exclusive wave offsets
    wpc[tid] = ys - y;
  }
  __syncthreads();
  float cS = S0 + wps[wid] + (is - ls);
  float cC = C0 + wpc[wid] + (ic - lc);
  int fidx = -1; float fS = 0.f, fC = 0.f;
#pragma unroll
  for (int i = 0; i < BPT; i++) {
    if (fidx < 0 && (cS + bs[i]) + (cC + bn[i]) - 1.f > Bd) {
      fidx = i; fS = cS; fC = cC;
    }
    cS += bs[i]; cC += bn[i];
  }
  if (fidx >= 0) atomicMin(&bc->first, (unsigned)tid);
  __syncthreads();
  if (bc->first == (unsigned)tid && fidx >= 0) {
    bc->bin = (unsigned)(tid * BPT + fidx);
    bc->S0 = fS; bc->K0 = fC;
    bc->m = hc[tid * BPT + fidx];
  } else if (bc->first == 0xFFFFFFFFu && tid == K2T - 1) {
    // razor-edge f32 inconsistency fallback: crossing at last bin
    bc->bin = (unsigned)(K2T * BPT - 1);
    bc->S0 = cS - bs[BPT - 1]; bc->K0 = cC - bn[BPT - 1];
    bc->m = hc[K2T * BPT - 1];
  }
  __syncthreads();
}

__global__ __launch_bounds__(K2T)
void select_kernel(const float* __restrict__ lv, float* __restrict__ outp, int B) {
  __shared__ float    hs[4096];
  __shared__ unsigned hc[4096];
  __shared__ float    tot_s[256];
  __shared__ float    tot_c[256];
  __shared__ float    wps[16], wpc[16];
  __shared__ BC bc;

  const int tid = threadIdx.x;
  const int lane = tid & 63, wid = tid >> 6;
  const float Bd = (float)B;

  // ---- load 32 values/thread (B == 32768 -> exact fit; pad +inf otherwise)
  float v[KPT];
#pragma unroll
  for (int i = 0; i < KPT / 4; i++) {
    int idx4 = tid + i * K2T;
    if (idx4 * 4 < B) {
      float4 t = ((const float4*)lv)[idx4];
      v[i*4+0] = t.x; v[i*4+1] = t.y; v[i*4+2] = t.z; v[i*4+3] = t.w;
    } else {
      v[i*4+0] = v[i*4+1] = v[i*4+2] = v[i*4+3] = INFINITY;
    }
  }

  // ---- count(margin < 0) == count(l > 1)
  float cn = 0.f;
#pragma unroll
  for (int i = 0; i < KPT; i++)
    if (v[i] > 1.0f && v[i] != INFINITY) cn += 1.f;
  cn = wave_sum_f(cn);
  if (lane == 0) wps[wid] = cn;
  __syncthreads();
  if (tid == 0) {
    float t = 0.f;
    for (int w = 0; w < 16; w++) t += wps[w];
    bc.cn = t;
    bc.selectAll = 0;
  }

  // ---- PASS 1: 256 exponent bins, per-wave sub-histograms (kill hot-bin atomics)
  __syncthreads();
  for (int i = tid; i < 4096; i += K2T) { hs[i] = 0.f; hc[i] = 0u; }
  __syncthreads();
  const int sub = wid << 8;
#pragma unroll
  for (int i = 0; i < KPT; i++) {
    if (v[i] != INFINITY) {
      unsigned b = __float_as_uint(v[i]) >> 23;   // 0..254 (l >= 0, finite)
      atomicAdd(&hc[sub + b], 1u);
      atomicAdd(&hs[sub + b], v[i]);
    }
  }
  __syncthreads();
  if (tid < 256) {
    float s = 0.f, c = 0.f;
    for (int w = 0; w < 16; w++) {
      s += hs[(w << 8) + tid];
      c += (float)hc[(w << 8) + tid];
    }
    tot_s[tid] = s; tot_c[tid] = c;
  }
  __syncthreads();
  // wave 0 scans the 256 bins (4 consecutive per lane)
  if (wid == 0) {
    const int b0 = lane * 4;
    float s0 = tot_s[b0+0], s1 = tot_s[b0+1], s2 = tot_s[b0+2], s3 = tot_s[b0+3];
    float c0 = tot_c[b0+0], c1 = tot_c[b0+1], c2 = tot_c[b0+2], c3 = tot_c[b0+3];
    float ls = s0+s1+s2+s3, lc = c0+c1+c2+c3;
    float is = wave_incl_scan(ls);
    float ic = wave_incl_scan(lc);
    float cS = is - ls, cC = ic - lc;   // exclusive
    int fbin = -1; float fS = 0.f, fC = 0.f;
    if (fbin < 0 && (cS+s0)+(cC+c0)-1.f > Bd) { fbin = b0+0; fS = cS; fC = cC; }
    cS += s0; cC += c0;
    if (fbin < 0 && (cS+s1)+(cC+c1)-1.f > Bd) { fbin = b0+1; fS = cS; fC = cC; }
    cS += s1; cC += c1;
    if (fbin < 0 && (cS+s2)+(cC+c2)-1.f > Bd) { fbin = b0+2; fS = cS; fC = cC; }
    cS += s2; cC += c2;
    if (fbin < 0 && (cS+s3)+(cC+c3)-1.f > Bd) { fbin = b0+3; fS = cS; fC = cC; }
    cS += s3; cC += c3;
    unsigned long long ball = __ballot(fbin >= 0);
    if (ball == 0ull) {
      if (lane == 63) { bc.selectAll = 1; bc.totS = is; bc.totC = ic; }
    } else {
      int fl = __ffsll((unsigned long long)ball) - 1;
      if (lane == fl) { bc.bin = (unsigned)fbin; bc.S0 = fS; bc.K0 = fC; }
    }
  }
  __syncthreads();

  if (!bc.selectAll) {
    // ---- PASS 2: 4096 bins over next 12 bits within exponent bin e*
    const unsigned estar = bc.bin;
    const float S1 = bc.S0, K1 = bc.K0;
    __syncthreads();
    for (int i = tid; i < 4096; i += K2T) { hs[i] = 0.f; hc[i] = 0u; }
    __syncthreads();
#pragma unroll
    for (int i = 0; i < KPT; i++) {
      unsigned b = __float_as_uint(v[i]);
      if (v[i] != INFINITY && (b >> 23) == estar) {
        unsigned k = (b >> 11) & 0xFFFu;
        atomicAdd(&hc[k], 1u);
        atomicAdd(&hs[k], v[i]);
      }
    }
    __syncthreads();
    find_crossing<4>(hs, hc, Bd, S1, K1, wps, wpc, &bc);

    // ---- PASS 3: 2048 bins over last 11 bits within 21-bit prefix
    const unsigned p2 = bc.bin;
    const unsigned pref21 = (estar << 12) | p2;
    const float S2 = bc.S0, K2 = bc.K0;
    __syncthreads();
    for (int i = tid; i < 2048; i += K2T) { hs[i] = 0.f; hc[i] = 0u; }
    __syncthreads();
#pragma unroll
    for (int i = 0; i < KPT; i++) {
      unsigned b = __float_as_uint(v[i]);
      if (v[i] != INFINITY && (b >> 11) == pref21) {
        unsigned k = b & 0x7FFu;
        atomicAdd(&hc[k], 1u);
        atomicAdd(&hs[k], v[i]);
      }
    }
    __syncthreads();
    find_crossing<2>(hs, hc, Bd, S2, K2, wps, wpc, &bc);

    if (tid == 0) {
      const unsigned pstar = (pref21 << 11) | bc.bin;
      const double vv = (double)__uint_as_float(pstar);
      const double S0 = (double)bc.S0, K0 = (double)bc.K0;
      const double m  = (double)bc.m;
      const double Bdd = (double)B;
      double j = floor((Bdd - S0 - K0 + 1.0) / (vv + 1.0));
      if (j < 0.0) j = 0.0;
      if (j > m) j = m;
      double loss1 = S0 + j * vv;
      double loss2 = Bdd - (K0 + j) + (double)bc.cn;
      outp[0] = (float)fmax(loss1, loss2);
    }
  } else {
    if (tid == 0) {
      double loss1 = (double)bc.totS;
      double loss2 = (double)B - (double)bc.totC + (double)bc.cn;
      outp[0] = (float)fmax(loss1, loss2);
    }
  }
}

extern "C" void kernel_launch(void* const* d_in, const int* in_sizes, int n_in,
                              void* d_out, int out_size, void* d_ws, size_t ws_size,
                              hipStream_t stream) {
  const float* outp  = (const float*)d_in[0];
  const int* target  = (const int*)d_in[1];
  const int B = in_sizes[1];
  const int C = in_sizes[0] / B;

  float* lv = (float*)d_ws;            // B floats = 128 KB scratch
  float* out = (float*)d_out;

  const int waves_per_block = 4;       // 256 threads, 1 row per wave
  dim3 grid((B + waves_per_block - 1) / waves_per_block);
  row_loss_kernel<<<grid, waves_per_block * WAVE, 0, stream>>>(outp, target, lv, B, C);
  select_kernel<<<1, K2T, 0, stream>>>(lv, out, B);
}